// Round 1
// baseline (415.070 us; speedup 1.0000x reference)
//
#include <hip/hip_runtime.h>
#include <math.h>

#define TOTAL_G 17064
#define NCAND   3064
#define BATCHN  16

// ws layout (bytes):
//   keys0: u64[16][16384]  @ 0         (2,097,152)
//   keys1: u64[16][4096]   @ 2,097,152 (  524,288)
//   score: f32[16][17064]  @ 2,621,440 (1,092,096)
//   clsi : i32[16][17064]  @ 3,713,536 (1,092,096)  -> total 4,805,632 B

struct Ptrs {
  const float *cls0,*cls1,*cls2,*cls3,*cls4;
  const float *reg0,*reg1,*reg2,*reg3,*reg4;
  const float *ctr0,*ctr1,*ctr2,*ctr3,*ctr4;
  const float *pos0,*pos1,*pos2,*pos3,*pos4;
  unsigned long long *keys0, *keys1;
  float *score; int *clsi;
};

__device__ __forceinline__ float sigd(float x) {
  return (float)(1.0 / (1.0 + exp(-(double)x)));
}
__device__ __forceinline__ float dexp(float x) {
  return (float)exp((double)x);
}
__device__ __forceinline__ void levinfo(int gid, int& lev, int& idx, int& nl) {
  if      (gid < 12800) { lev=0; idx=gid;        nl=12800; }
  else if (gid < 16000) { lev=1; idx=gid-12800;  nl=3200;  }
  else if (gid < 16800) { lev=2; idx=gid-16000;  nl=800;   }
  else if (gid < 17008) { lev=3; idx=gid-16800;  nl=208;   }
  else                  { lev=4; idx=gid-17008;  nl=56;    }
}

// concat position c (0..3063) -> global candidate id within image b.
// Requires keys0/keys1 already sorted.
__device__ __forceinline__ int mapgid(const Ptrs& P, int b, int c) {
  if (c < 1000) return (int)(P.keys0[b * 16384 + c] & 0xFFFFFFFFull);
  if (c < 2000) return 12800 + (int)(P.keys1[b * 4096 + (c - 1000)] & 0xFFFFFFFFull);
  if (c < 2800) return 16000 + (c - 2000);
  if (c < 3008) return 16800 + (c - 2800);
  return 17008 + (c - 3008);
}

// ---------------- K1: per-position score / argmax / sort-key ----------------
__global__ __launch_bounds__(256) void k_score(Ptrs P) {
  int w    = (blockIdx.x * 256 + threadIdx.x) >> 6;   // wave id = (b, g)
  int lane = threadIdx.x & 63;
  if (w >= BATCHN * TOTAL_G) return;
  int b = w / TOTAL_G;
  int g = w - b * TOTAL_G;

  int lev, idx, nl;
  levinfo(g, lev, idx, nl);
  const float *clsb, *ctrb;
  if      (lev == 0) { clsb = P.cls0; ctrb = P.ctr0; }
  else if (lev == 1) { clsb = P.cls1; ctrb = P.ctr1; }
  else if (lev == 2) { clsb = P.cls2; ctrb = P.ctr2; }
  else if (lev == 3) { clsb = P.cls3; ctrb = P.ctr3; }
  else               { clsb = P.cls4; ctrb = P.ctr4; }

  const float* cp = clsb + (size_t)(b * nl + idx) * 80;
  float x0 = cp[lane];
  float x1 = (lane < 16) ? cp[64 + lane] : -INFINITY;

  // logit max with first-index tie-break
  float v = x0; int vi = lane;
  if (x1 > v) { v = x1; vi = 64 + lane; }
  for (int o = 32; o > 0; o >>= 1) {
    float ov = __shfl_down(v, o);
    int   oi = __shfl_down(vi, o);
    if (ov > v || (ov == v && oi < vi)) { v = ov; vi = oi; }
  }
  float m = __shfl(v, 0);

  // Candidates whose fp32 sigmoid could tie the max sigmoid: |x-m| <= 1e-3
  // (covers all possible fp32-sigmoid ties for logits |x| < ~8).
  bool c0 = (x0 >= m - 1e-3f);
  bool c1 = (lane < 16) && (x1 >= m - 1e-3f);
  unsigned long long bl0 = __ballot(c0);
  unsigned long long bl1 = __ballot(c1);
  int ncand = __popcll(bl0) + __popcll(bl1);

  float pvR = -1.0f; int piR = 0x7fffffff;
  if (ncand > 1) {
    // exact per-element sigmoid argmax (first index wins ties) among candidates
    float pv = -1.0f; int pi = 0x7fffffff;
    if (c0) { pv = sigd(x0); pi = lane; }
    if (c1) { float p1 = sigd(x1); if (p1 > pv) { pv = p1; pi = 64 + lane; } }
    for (int o = 32; o > 0; o >>= 1) {
      float ov = __shfl_down(pv, o);
      int   oi = __shfl_down(pi, o);
      if (ov > pv || (ov == pv && oi < pi)) { pv = ov; pi = oi; }
    }
    pvR = pv; piR = pi;
  }

  if (lane == 0) {
    float pmax; int ci;
    if (ncand > 1) { pmax = pvR; ci = piR; }
    else           { pmax = sigd(v); ci = vi; }
    float t = ctrb[(size_t)b * nl + idx];
    float csig = sigd(t);
    float prod = pmax * csig;                    // fp32 mul (matches ref)
    float s = (float)sqrt((double)prod);         // correctly-rounded f32 sqrt
    P.score[b * TOTAL_G + g] = s;
    P.clsi [b * TOTAL_G + g] = ci;
    unsigned sb = __float_as_uint(s);            // s >= 0 -> bit order == value order
    unsigned long long key = ((unsigned long long)(~sb) << 32) | (unsigned)idx;
    if      (lev == 0) P.keys0[b * 16384 + idx] = key;
    else if (lev == 1) P.keys1[b * 4096  + idx] = key;
  }
}

// ---------------- bitonic sort of 4096 u64 keys in LDS ----------------
__device__ __forceinline__ void bitonic4096(unsigned long long* k) {
  for (int kk = 2; kk <= 4096; kk <<= 1) {
    for (int j = kk >> 1; j > 0; j >>= 1) {
      for (int t = threadIdx.x; t < 4096; t += blockDim.x) {
        int ixj = t ^ j;
        if (ixj > t) {
          unsigned long long a = k[t], c = k[ixj];
          bool up = ((t & kk) == 0);
          if ((a > c) == up) { k[t] = c; k[ixj] = a; }
        }
      }
      __syncthreads();
    }
  }
}

// K2a: sort each 4096-chunk (level0: 16*4 chunks, level1: 16 arrays)
__global__ __launch_bounds__(1024) void k_sortchunks(Ptrs P) {
  __shared__ unsigned long long sk[4096];
  int bid = blockIdx.x;
  unsigned long long* src;
  if (bid < 64) src = P.keys0 + (size_t)(bid >> 2) * 16384 + (size_t)(bid & 3) * 4096;
  else          src = P.keys1 + (size_t)(bid - 64) * 4096;
  for (int t = threadIdx.x; t < 4096; t += 1024) sk[t] = src[t];
  __syncthreads();
  bitonic4096(sk);
  for (int t = threadIdx.x; t < 4096; t += 1024) src[t] = sk[t];
}

// K2b: merge level-0 chunk-tops (top-1000 of 12800 is within the union of
// the four per-chunk top-1024s). Result: keys0[b][0..4095] sorted, first 1000 = top_k.
__global__ __launch_bounds__(1024) void k_merge0(Ptrs P) {
  __shared__ unsigned long long sk[4096];
  int b = blockIdx.x;
  unsigned long long* base = P.keys0 + (size_t)b * 16384;
  for (int t = threadIdx.x; t < 4096; t += 1024)
    sk[t] = base[(size_t)(t >> 10) * 4096 + (t & 1023)];
  __syncthreads();
  bitonic4096(sk);
  for (int t = threadIdx.x; t < 4096; t += 1024) base[t] = sk[t];
}

// ---------------- K3: per-image global sort + box decode + NMS + output ----------------
struct SM3 {
  union {
    unsigned long long key[4096];   // 32 KB (sort phase)
    float box[NCAND * 4];           // 49 KB (NMS phase)
  } u;
  unsigned short sortedc[4096];     // concat pos by rank
  unsigned long long live[48];      // 3064 live bits
  unsigned short keeplist[100];
  int slotgid[100];
  int cur;
};

__global__ __launch_bounds__(1024) void k_nms(Ptrs P, float* out) {
  __shared__ SM3 sm;
  int b = blockIdx.x;
  int tid = threadIdx.x;

  // phase 0: build keys (high = valid ? ~score_bits : FFFF, low = concat pos)
  for (int c = tid; c < 4096; c += 1024) {
    unsigned long long key;
    if (c < NCAND) {
      int gid = mapgid(P, b, c);
      float s = P.score[b * TOTAL_G + gid];
      unsigned hi = (s > 0.01f) ? ~__float_as_uint(s) : 0xFFFFFFFFu;
      key = ((unsigned long long)hi << 32) | (unsigned)c;
    } else {
      key = 0xFFFFFFFFFFFFFFFFull;
    }
    sm.u.key[c] = key;
  }
  __syncthreads();

  // phase 1: stable-equivalent sort: (score desc, concat pos asc), invalid last
  bitonic4096(sm.u.key);

  // phase 2: extract order + live bits
  if (tid < 48) sm.live[tid] = 0ull;
  __syncthreads();
  for (int r = tid; r < 4096; r += 1024) {
    unsigned long long kk = sm.u.key[r];
    unsigned c = (unsigned)(kk & 0xFFFFFFFFull);
    sm.sortedc[r] = (c >= 4096u) ? (unsigned short)0xFFFF : (unsigned short)c;
    if (r < NCAND && (unsigned)(kk >> 32) != 0xFFFFFFFFu)
      atomicOr(&sm.live[r >> 6], 1ull << (r & 63));
  }
  __syncthreads();

  // phase 3: decode boxes into the (now free) key region
  for (int r = tid; r < NCAND; r += 1024) {
    int c = sm.sortedc[r];                 // first 3064 ranks are always real
    int gid = mapgid(P, b, c);
    int lev, idx, nl; levinfo(gid, lev, idx, nl);
    const float *rp, *pp;
    if      (lev == 0) { rp = P.reg0; pp = P.pos0; }
    else if (lev == 1) { rp = P.reg1; pp = P.pos1; }
    else if (lev == 2) { rp = P.reg2; pp = P.pos2; }
    else if (lev == 3) { rp = P.reg3; pp = P.pos3; }
    else               { rp = P.reg4; pp = P.pos4; }
    rp += (size_t)(b * nl + idx) * 4;
    pp += (size_t)(b * nl + idx) * 2;
    float e0 = dexp(rp[0]), e1 = dexp(rp[1]), e2 = dexp(rp[2]), e3 = dexp(rp[3]);
    float px = pp[0], py = pp[1];
    float x1 = truncf(px - e0), y1 = truncf(py - e1);
    float x2 = truncf(px + e2), y2 = truncf(py + e3);
    x1 = fmaxf(x1, 0.0f); y1 = fmaxf(y1, 0.0f);
    x2 = fminf(x2, 1023.0f); y2 = fminf(y2, 799.0f);
    sm.u.box[r*4+0] = x1; sm.u.box[r*4+1] = y1;
    sm.u.box[r*4+2] = x2; sm.u.box[r*4+3] = y2;
  }
  __syncthreads();

  // phase 4: greedy NMS — next live item is always kept; stop at 100 kept
  int kept = 0, start = 0;
  while (kept < 100) {
    if (tid == 0) {
      int nxt = -1;
      int w = start >> 6;
      unsigned long long mask = (w < 48) ? (sm.live[w] & (~0ull << (start & 63))) : 0ull;
      while (w < 48) {
        if (mask) { nxt = (w << 6) + __ffsll((unsigned long long)mask) - 1; break; }
        ++w;
        if (w < 48) mask = sm.live[w];
      }
      sm.cur = nxt;
      if (nxt >= 0) sm.keeplist[kept] = (unsigned short)nxt;
    }
    __syncthreads();
    int i = sm.cur;
    if (i < 0) break;
    float ix1 = sm.u.box[i*4+0], iy1 = sm.u.box[i*4+1];
    float ix2 = sm.u.box[i*4+2], iy2 = sm.u.box[i*4+3];
    float ia  = (ix2 - ix1) * (iy2 - iy1);
    for (int j = i + 1 + tid; j < NCAND; j += 1024) {
      if (!((sm.live[j >> 6] >> (j & 63)) & 1ull)) continue;
      float jx1 = sm.u.box[j*4+0], jy1 = sm.u.box[j*4+1];
      float jx2 = sm.u.box[j*4+2], jy2 = sm.u.box[j*4+3];
      float ja  = (jx2 - jx1) * (jy2 - jy1);
      float ltx = fmaxf(ix1, jx1), lty = fmaxf(iy1, jy1);
      float rbx = fminf(ix2, jx2), rby = fminf(iy2, jy2);
      float wv = fmaxf(rbx - ltx, 0.0f), hv = fmaxf(rby - lty, 0.0f);
      float inter = wv * hv;
      float iou = inter / (ia + ja - inter);     // exact: integer-valued fp32
      if (iou > 0.6f) atomicAnd(&sm.live[j >> 6], ~(1ull << (j & 63)));
    }
    __syncthreads();
    kept++;
    start = i + 1;
  }

  // phase 5: outputs.  out_s @0 [16,100], out_c @1600, out_b @3200 [16,100,4],
  // out_cp @9600 [16,100,80]
  if (tid < 100) {
    int s = tid;
    float os = -1.0f, oc = -1.0f, b0 = -1.0f, b1 = -1.0f, b2 = -1.0f, b3 = -1.0f;
    int gid = -1;
    if (s < kept) {
      int r = sm.keeplist[s];
      int c = sm.sortedc[r];
      gid = mapgid(P, b, c);
      os = P.score[b * TOTAL_G + gid];
      oc = (float)P.clsi[b * TOTAL_G + gid];
      b0 = sm.u.box[r*4+0]; b1 = sm.u.box[r*4+1];
      b2 = sm.u.box[r*4+2]; b3 = sm.u.box[r*4+3];
    }
    sm.slotgid[s] = gid;
    out[b * 100 + s] = os;
    out[1600 + b * 100 + s] = oc;
    float* ob = out + 3200 + (size_t)(b * 100 + s) * 4;
    ob[0] = b0; ob[1] = b1; ob[2] = b2; ob[3] = b3;
  }
  __syncthreads();
  for (int t = tid; t < 100 * 80; t += 1024) {
    int s = t / 80, k = t - s * 80;
    float val = -1.0f;
    int gid = sm.slotgid[s];
    if (gid >= 0) {
      int lev, idx, nl; levinfo(gid, lev, idx, nl);
      const float* cp;
      if      (lev == 0) cp = P.cls0;
      else if (lev == 1) cp = P.cls1;
      else if (lev == 2) cp = P.cls2;
      else if (lev == 3) cp = P.cls3;
      else               cp = P.cls4;
      val = sigd(cp[(size_t)(b * nl + idx) * 80 + k]);
    }
    out[9600 + (size_t)(b * 100 + s) * 80 + k] = val;
  }
}

extern "C" void kernel_launch(void* const* d_in, const int* in_sizes, int n_in,
                              void* d_out, int out_size, void* d_ws, size_t ws_size,
                              hipStream_t stream) {
  (void)in_sizes; (void)n_in; (void)out_size; (void)ws_size;
  Ptrs P;
  P.cls0 = (const float*)d_in[0];  P.reg0 = (const float*)d_in[1];
  P.ctr0 = (const float*)d_in[2];  P.pos0 = (const float*)d_in[3];
  P.cls1 = (const float*)d_in[4];  P.reg1 = (const float*)d_in[5];
  P.ctr1 = (const float*)d_in[6];  P.pos1 = (const float*)d_in[7];
  P.cls2 = (const float*)d_in[8];  P.reg2 = (const float*)d_in[9];
  P.ctr2 = (const float*)d_in[10]; P.pos2 = (const float*)d_in[11];
  P.cls3 = (const float*)d_in[12]; P.reg3 = (const float*)d_in[13];
  P.ctr3 = (const float*)d_in[14]; P.pos3 = (const float*)d_in[15];
  P.cls4 = (const float*)d_in[16]; P.reg4 = (const float*)d_in[17];
  P.ctr4 = (const float*)d_in[18]; P.pos4 = (const float*)d_in[19];

  char* ws = (char*)d_ws;
  P.keys0 = (unsigned long long*)(ws);
  P.keys1 = (unsigned long long*)(ws + 2097152);
  P.score = (float*)(ws + 2621440);
  P.clsi  = (int*)  (ws + 3713536);

  // pad keys with all-ones so pads sort last
  (void)hipMemsetAsync(d_ws, 0xFF, 2621440, stream);

  // 16*17064 waves, 4 waves per 256-thread block
  k_score<<<68256, 256, 0, stream>>>(P);
  k_sortchunks<<<80, 1024, 0, stream>>>(P);
  k_merge0<<<16, 1024, 0, stream>>>(P);
  k_nms<<<16, 1024, 0, stream>>>(P, (float*)d_out);
}

// Round 2
// 227.468 us; speedup vs baseline: 1.8247x; 1.8247x over previous
//
#include <hip/hip_runtime.h>
#include <math.h>

#define TOTAL_G 17064
#define NCAND   3064
#define BATCHN  16
#define ALLF    0xFFFFFFFFFFFFFFFFull
// valid <=> score > 0.01f <=> scorebits > 0x3C23D70A <=> hi=~sb < 0xC3DC28F5
#define INVALID_HI 0xC3DC28F5u

typedef unsigned long long u64;

// ws layout (bytes):
//   keys0 : u64[16][16384] @ 0          (2,097,152)
//   keys1 : u64[16][4096]  @ 2,097,152  (  524,288)
//   keys2 : u64[16][1024]  @ 2,621,440  (  131,072)
//   keys34: u64[16][1024]  @ 2,752,512  (  131,072)
//   score : f32[16][17064] @ 2,883,584  (1,092,096)
//   clsi  : u16[16][17064] @ 3,975,680  (  546,048)  -> total 4,521,728 B

struct Ptrs {
  const float *cls0,*cls1,*cls2,*cls3,*cls4;
  const float *reg0,*reg1,*reg2,*reg3,*reg4;
  const float *ctr0,*ctr1,*ctr2,*ctr3,*ctr4;
  const float *pos0,*pos1,*pos2,*pos3,*pos4;
  u64 *keys0, *keys1, *keys2, *keys34;
  float *score; unsigned short *clsi;
};

__device__ __forceinline__ float sigd(float x) {
  return (float)(1.0 / (1.0 + exp(-(double)x)));
}
__device__ __forceinline__ float dexp(float x) {
  return (float)exp((double)x);
}
__device__ __forceinline__ void levinfo(int gid, int& lev, int& idx, int& nl) {
  if      (gid < 12800) { lev=0; idx=gid;        nl=12800; }
  else if (gid < 16000) { lev=1; idx=gid-12800;  nl=3200;  }
  else if (gid < 16800) { lev=2; idx=gid-16000;  nl=800;   }
  else if (gid < 17008) { lev=3; idx=gid-16800;  nl=208;   }
  else                  { lev=4; idx=gid-17008;  nl=56;    }
}

// concat position c (0..3063) -> global candidate id within image b.
// Requires keys0 merged (k_merge0) and keys1 sorted.
__device__ __forceinline__ int mapgid(const Ptrs& P, int b, int c) {
  if (c < 1000) return (int)(P.keys0[(size_t)b * 16384 + c] & 0xFFFFFFFFull);
  if (c < 2000) return 12800 + (int)(P.keys1[(size_t)b * 4096 + (c - 1000)] & 0xFFFFFFFFull);
  return 16000 + (c - 2000);
}

// ---------------- K1: thread-per-position score / argmax / sort-key ----------------
__global__ __launch_bounds__(256) void k_score(Ptrs P) {
  int g = blockIdx.x * 256 + threadIdx.x;
  if (g >= TOTAL_G) return;
  int b = blockIdx.y;

  int lev, idx, nl;
  levinfo(g, lev, idx, nl);
  const float *clsb, *ctrb;
  if      (lev == 0) { clsb = P.cls0; ctrb = P.ctr0; }
  else if (lev == 1) { clsb = P.cls1; ctrb = P.ctr1; }
  else if (lev == 2) { clsb = P.cls2; ctrb = P.ctr2; }
  else if (lev == 3) { clsb = P.cls3; ctrb = P.ctr3; }
  else               { clsb = P.cls4; ctrb = P.ctr4; }

  const float4* cp4 = (const float4*)(clsb + (size_t)(b * nl + idx) * 80);
  float4 q[20];
  #pragma unroll
  for (int k = 0; k < 20; ++k) q[k] = cp4[k];

  // logit max, first-index tie-break (strict >)
  float m = -INFINITY; int mi = 0;
  #pragma unroll
  for (int k = 0; k < 20; ++k) {
    if (q[k].x > m) { m = q[k].x; mi = 4*k+0; }
    if (q[k].y > m) { m = q[k].y; mi = 4*k+1; }
    if (q[k].z > m) { m = q[k].z; mi = 4*k+2; }
    if (q[k].w > m) { m = q[k].w; mi = 4*k+3; }
  }
  // candidates whose fp32 sigmoid could tie the max's sigmoid
  float thr = fminf(m - 1e-3f, 9.0f);
  int cnt = 0;
  #pragma unroll
  for (int k = 0; k < 20; ++k) {
    cnt += (q[k].x >= thr) + (q[k].y >= thr) + (q[k].z >= thr) + (q[k].w >= thr);
  }
  float pmax; int ci;
  if (cnt > 1) {
    // exact per-element sigmoid argmax, first index wins ties
    pmax = -1.0f; ci = 0;
    #pragma unroll
    for (int k = 0; k < 20; ++k) {
      float xs[4] = {q[k].x, q[k].y, q[k].z, q[k].w};
      #pragma unroll
      for (int e = 0; e < 4; ++e) {
        if (xs[e] >= thr) {
          float p = sigd(xs[e]);
          if (p > pmax) { pmax = p; ci = 4*k+e; }
        }
      }
    }
  } else {
    pmax = sigd(m); ci = mi;
  }

  float t = ctrb[(size_t)b * nl + idx];
  float csig = sigd(t);
  float prod = pmax * csig;                 // fp32 mul (matches ref)
  float s = (float)sqrt((double)prod);      // correctly-rounded f32 sqrt
  P.score[(size_t)b * TOTAL_G + g] = s;
  P.clsi [(size_t)b * TOTAL_G + g] = (unsigned short)ci;

  unsigned sb = __float_as_uint(s);
  unsigned hi = ~sb;
  if      (lev == 0) P.keys0 [(size_t)b * 16384 + idx]       = ((u64)hi << 32) | (unsigned)idx;
  else if (lev == 1) P.keys1 [(size_t)b * 4096  + idx]       = ((u64)hi << 32) | (unsigned)idx;
  else if (lev == 2) P.keys2 [(size_t)b * 1024  + idx]       = ((u64)hi << 32) | (unsigned)(2000 + idx);
  else if (lev == 3) P.keys34[(size_t)b * 1024  + idx]       = ((u64)hi << 32) | (unsigned)(2800 + idx);
  else               P.keys34[(size_t)b * 1024  + 208 + idx] = ((u64)hi << 32) | (unsigned)(3008 + idx);
}

// ---------------- bitonic network helpers (in LDS) ----------------
// runs stages kk = kk0 .. n. kk0=2 -> full sort; kk0=n -> final merge only.
__device__ __forceinline__ void bitonic_range(u64* k, int n, int kk0) {
  for (int kk = kk0; kk <= n; kk <<= 1) {
    for (int j = kk >> 1; j > 0; j >>= 1) {
      for (int t = threadIdx.x; t < n; t += blockDim.x) {
        int ixj = t ^ j;
        if (ixj > t) {
          u64 a = k[t], c = k[ixj];
          bool up = ((t & kk) == 0);
          if ((a > c) == up) { k[t] = c; k[ixj] = a; }
        }
      }
      __syncthreads();
    }
  }
}

// K2a: sort chunks. bid<64: level0 4096-chunks; <80: level1 (4096);
//      <96: level2 (1024); <112: levels3+4 (512 prefix of the 1024 region).
__global__ __launch_bounds__(1024) void k_sortchunks(Ptrs P) {
  __shared__ u64 sk[4096];
  int bid = blockIdx.x;
  u64* src; int n;
  if      (bid < 64) { src = P.keys0  + (size_t)(bid >> 2) * 16384 + (size_t)(bid & 3) * 4096; n = 4096; }
  else if (bid < 80) { src = P.keys1  + (size_t)(bid - 64) * 4096; n = 4096; }
  else if (bid < 96) { src = P.keys2  + (size_t)(bid - 80) * 1024; n = 1024; }
  else               { src = P.keys34 + (size_t)(bid - 96) * 1024; n = 512;  }
  for (int t = threadIdx.x; t < n; t += 1024) sk[t] = src[t];
  __syncthreads();
  bitonic_range(sk, n, 2);
  for (int t = threadIdx.x; t < n; t += 1024) src[t] = sk[t];
}

// K2b: merge the four level-0 chunk top-1024s (top-1000 of 12800 is within the
// union). Load asc/desc/asc/desc, run stages kk=2048,4096 (23 passes).
__global__ __launch_bounds__(1024) void k_merge0(Ptrs P) {
  __shared__ u64 sk[4096];
  int b = blockIdx.x;
  u64* base = P.keys0 + (size_t)b * 16384;
  for (int t = threadIdx.x; t < 4096; t += 1024) {
    int blk = t >> 10, pos = t & 1023;
    u64 e = base[(size_t)blk * 4096 + pos];
    int dst = (blk & 1) ? (blk << 10) + (1023 - pos) : t;
    sk[dst] = e;
  }
  __syncthreads();
  bitonic_range(sk, 4096, 2048);
  for (int t = threadIdx.x; t < 4096; t += 1024) base[t] = sk[t];
}

// ---------------- K3: per-image merge + decode + bitmask NMS + output ----------------
struct SM3 {
  union {
    u64 key[4096];          // 32 KB (merge phase)
    float box[NCAND * 4];   // 49 KB (NMS phase)
  } u;
  u64 mask[512 * 8];        // 32 KB: mask[i][w] = ranks j>i (word w) with IoU>thr
  unsigned short sortedc[4096];
  u64 live48[48];           // valid bits for all ranks (fallback path)
  u64 live8[8];             // valid bits for ranks < 512
  unsigned short keeplist[100];
  int slotgid[100];
  int kept;
  int cur;
};

__global__ __launch_bounds__(1024) void k_nms(Ptrs P, float* out) {
  __shared__ SM3 sm;
  int b = blockIdx.x;
  int tid = threadIdx.x;

  // phase 0: load 4 pre-sorted 1024-blocks as a bitonic sequence with final keys
  for (int t = tid; t < 4096; t += 1024) {
    int blk = t >> 10, pos = t & 1023;
    u64 e;
    if      (blk == 0) e = (pos < 1000) ? P.keys0[(size_t)b * 16384 + pos] : ALLF;
    else if (blk == 1) e = (pos < 1000) ? P.keys1[(size_t)b * 4096  + pos] : ALLF;
    else if (blk == 2) e = P.keys2 [(size_t)b * 1024 + pos];
    else               e = P.keys34[(size_t)b * 1024 + pos];
    unsigned hi = (unsigned)(e >> 32);
    u64 key;
    if (hi >= INVALID_HI) key = ALLF;   // invalid score or pad -> sorts last
    else {
      unsigned lo = (blk < 2) ? (unsigned)(blk * 1000 + pos) : (unsigned)e;
      key = ((u64)hi << 32) | lo;
    }
    int dst = (blk & 1) ? (blk << 10) + (1023 - pos) : t;
    sm.u.key[dst] = key;
  }
  if (tid < 48) sm.live48[tid] = 0ull;
  if (tid < 8)  sm.live8[tid]  = 0ull;
  __syncthreads();

  // phase 1: 23-pass bitonic merge -> globally sorted by (score desc, c asc)
  bitonic_range(sm.u.key, 4096, 2048);

  // phase 2: extract order + validity bits
  for (int r = tid; r < 4096; r += 1024) {
    u64 kk = sm.u.key[r];
    unsigned c = (unsigned)(kk & 0xFFFFFFFFull);
    sm.sortedc[r] = (c >= 4096u) ? (unsigned short)0xFFFF : (unsigned short)c;
    if (r < NCAND && (unsigned)(kk >> 32) != 0xFFFFFFFFu) {
      atomicOr(&sm.live48[r >> 6], 1ull << (r & 63));
      if (r < 512) atomicOr(&sm.live8[r >> 6], 1ull << (r & 63));
    }
  }
  __syncthreads();

  // phase 3: decode boxes into the (now free) key region
  for (int r = tid; r < NCAND; r += 1024) {
    int c = sm.sortedc[r];
    if (c == 0xFFFF) {
      sm.u.box[r*4+0] = -1e30f; sm.u.box[r*4+1] = -1e30f;
      sm.u.box[r*4+2] = -1e30f; sm.u.box[r*4+3] = -1e30f;
      continue;
    }
    int gid = mapgid(P, b, c);
    int lev, idx, nl; levinfo(gid, lev, idx, nl);
    const float *rp, *pp;
    if      (lev == 0) { rp = P.reg0; pp = P.pos0; }
    else if (lev == 1) { rp = P.reg1; pp = P.pos1; }
    else if (lev == 2) { rp = P.reg2; pp = P.pos2; }
    else if (lev == 3) { rp = P.reg3; pp = P.pos3; }
    else               { rp = P.reg4; pp = P.pos4; }
    rp += (size_t)(b * nl + idx) * 4;
    pp += (size_t)(b * nl + idx) * 2;
    float e0 = dexp(rp[0]), e1 = dexp(rp[1]), e2 = dexp(rp[2]), e3 = dexp(rp[3]);
    float px = pp[0], py = pp[1];
    float x1 = truncf(px - e0), y1 = truncf(py - e1);
    float x2 = truncf(px + e2), y2 = truncf(py + e3);
    x1 = fmaxf(x1, 0.0f); y1 = fmaxf(y1, 0.0f);
    x2 = fminf(x2, 1023.0f); y2 = fminf(y2, 799.0f);
    sm.u.box[r*4+0] = x1; sm.u.box[r*4+1] = y1;
    sm.u.box[r*4+2] = x2; sm.u.box[r*4+3] = y2;
  }
  __syncthreads();

  // phase 4a: suppression bit-matrix for the top-512 ranks (i suppresses j>i)
  for (int t4 = tid; t4 < 512 * 8; t4 += 1024) {
    int i = t4 >> 3, w = t4 & 7;
    u64 mword = 0;
    int jbase = w << 6;
    if (jbase + 63 > i) {
      float ix1 = sm.u.box[i*4+0], iy1 = sm.u.box[i*4+1];
      float ix2 = sm.u.box[i*4+2], iy2 = sm.u.box[i*4+3];
      float ia  = (ix2 - ix1) * (iy2 - iy1);
      #pragma unroll 4
      for (int bj = 0; bj < 64; ++bj) {
        int j = jbase + bj;
        if (j <= i) continue;
        float jx1 = sm.u.box[j*4+0], jy1 = sm.u.box[j*4+1];
        float jx2 = sm.u.box[j*4+2], jy2 = sm.u.box[j*4+3];
        float ja  = (jx2 - jx1) * (jy2 - jy1);
        float ltx = fmaxf(ix1, jx1), lty = fmaxf(iy1, jy1);
        float rbx = fminf(ix2, jx2), rby = fminf(iy2, jy2);
        float wv = fmaxf(rbx - ltx, 0.0f), hv = fmaxf(rby - lty, 0.0f);
        float inter = wv * hv;
        float iou = inter / (ia + ja - inter);   // exact: integer-valued fp32
        if (iou > 0.6f) mword |= (1ull << bj);
      }
    }
    sm.mask[t4] = mword;
  }
  __syncthreads();

  // phase 4b: single-wave barrier-free greedy reduce over ranks [0,512)
  if (tid < 64) {
    int lane = tid;
    u64 lw = (lane < 8) ? sm.live8[lane] : 0ull;
    int kept = 0;
    while (kept < 100) {
      bool nz = (lane < 8) && (lw != 0ull);
      u64 bal = __ballot(nz);
      if (!bal) break;
      int W = __ffsll(bal) - 1;
      u64 wv = __shfl(lw, W);
      int bit = __ffsll(wv) - 1;
      int i = (W << 6) + bit;
      if (lane == 0) sm.keeplist[kept] = (unsigned short)i;
      kept++;
      if (lane == W) lw &= ~(1ull << bit);
      if (kept == 100) break;
      if (lane < 8) lw &= ~sm.mask[i * 8 + lane];
    }
    if (lane == 0) sm.kept = kept;
  }
  __syncthreads();
  int kept = sm.kept;

  // phase 4c: fallback — 100th keep beyond rank 512 (rare; must stay correct)
  if (kept < 100) {
    // seed: suppress j >= 512 by all already-kept items
    for (int k2 = 0; k2 < kept; ++k2) {
      int i = sm.keeplist[k2];
      float ix1 = sm.u.box[i*4+0], iy1 = sm.u.box[i*4+1];
      float ix2 = sm.u.box[i*4+2], iy2 = sm.u.box[i*4+3];
      float ia  = (ix2 - ix1) * (iy2 - iy1);
      for (int j = 512 + tid; j < NCAND; j += 1024) {
        if (!((sm.live48[j >> 6] >> (j & 63)) & 1ull)) continue;
        float jx1 = sm.u.box[j*4+0], jy1 = sm.u.box[j*4+1];
        float jx2 = sm.u.box[j*4+2], jy2 = sm.u.box[j*4+3];
        float ja  = (jx2 - jx1) * (jy2 - jy1);
        float ltx = fmaxf(ix1, jx1), lty = fmaxf(iy1, jy1);
        float rbx = fminf(ix2, jx2), rby = fminf(iy2, jy2);
        float wv = fmaxf(rbx - ltx, 0.0f), hv = fmaxf(rby - lty, 0.0f);
        float inter = wv * hv;
        float iou = inter / (ia + ja - inter);
        if (iou > 0.6f) atomicAnd(&sm.live48[j >> 6], ~(1ull << (j & 63)));
      }
    }
    __syncthreads();
    int start = 512;
    while (kept < 100) {
      if (tid == 0) {
        int nxt = -1;
        int w = start >> 6;
        u64 mask = (w < 48) ? (sm.live48[w] & (~0ull << (start & 63))) : 0ull;
        while (w < 48) {
          if (mask) { nxt = (w << 6) + __ffsll(mask) - 1; break; }
          ++w;
          if (w < 48) mask = sm.live48[w];
        }
        sm.cur = nxt;
        if (nxt >= 0) sm.keeplist[kept] = (unsigned short)nxt;
      }
      __syncthreads();
      int i = sm.cur;
      if (i < 0) break;
      float ix1 = sm.u.box[i*4+0], iy1 = sm.u.box[i*4+1];
      float ix2 = sm.u.box[i*4+2], iy2 = sm.u.box[i*4+3];
      float ia  = (ix2 - ix1) * (iy2 - iy1);
      for (int j = i + 1 + tid; j < NCAND; j += 1024) {
        if (!((sm.live48[j >> 6] >> (j & 63)) & 1ull)) continue;
        float jx1 = sm.u.box[j*4+0], jy1 = sm.u.box[j*4+1];
        float jx2 = sm.u.box[j*4+2], jy2 = sm.u.box[j*4+3];
        float ja  = (jx2 - jx1) * (jy2 - jy1);
        float ltx = fmaxf(ix1, jx1), lty = fmaxf(iy1, jy1);
        float rbx = fminf(ix2, jx2), rby = fminf(iy2, jy2);
        float wv = fmaxf(rbx - ltx, 0.0f), hv = fmaxf(rby - lty, 0.0f);
        float inter = wv * hv;
        float iou = inter / (ia + ja - inter);
        if (iou > 0.6f) atomicAnd(&sm.live48[j >> 6], ~(1ull << (j & 63)));
      }
      __syncthreads();
      kept++;
      start = i + 1;
    }
  }

  // phase 5: outputs. out_s @0 [16,100], out_c @1600, out_b @3200 [16,100,4],
  // out_cp @9600 [16,100,80]
  if (tid < 100) {
    int s = tid;
    float os = -1.0f, oc = -1.0f, b0 = -1.0f, b1 = -1.0f, b2 = -1.0f, b3 = -1.0f;
    int gid = -1;
    if (s < kept) {
      int r = sm.keeplist[s];
      int c = sm.sortedc[r];
      gid = mapgid(P, b, c);
      os = P.score[(size_t)b * TOTAL_G + gid];
      oc = (float)P.clsi[(size_t)b * TOTAL_G + gid];
      b0 = sm.u.box[r*4+0]; b1 = sm.u.box[r*4+1];
      b2 = sm.u.box[r*4+2]; b3 = sm.u.box[r*4+3];
    }
    sm.slotgid[s] = gid;
    out[b * 100 + s] = os;
    out[1600 + b * 100 + s] = oc;
    float* ob = out + 3200 + (size_t)(b * 100 + s) * 4;
    ob[0] = b0; ob[1] = b1; ob[2] = b2; ob[3] = b3;
  }
  __syncthreads();
  for (int t = tid; t < 100 * 80; t += 1024) {
    int s = t / 80, k = t - s * 80;
    float val = -1.0f;
    int gid = sm.slotgid[s];
    if (gid >= 0) {
      int lev, idx, nl; levinfo(gid, lev, idx, nl);
      const float* cp;
      if      (lev == 0) cp = P.cls0;
      else if (lev == 1) cp = P.cls1;
      else if (lev == 2) cp = P.cls2;
      else if (lev == 3) cp = P.cls3;
      else               cp = P.cls4;
      val = sigd(cp[(size_t)(b * nl + idx) * 80 + k]);
    }
    out[9600 + (size_t)(b * 100 + s) * 80 + k] = val;
  }
}

extern "C" void kernel_launch(void* const* d_in, const int* in_sizes, int n_in,
                              void* d_out, int out_size, void* d_ws, size_t ws_size,
                              hipStream_t stream) {
  (void)in_sizes; (void)n_in; (void)out_size; (void)ws_size;
  Ptrs P;
  P.cls0 = (const float*)d_in[0];  P.reg0 = (const float*)d_in[1];
  P.ctr0 = (const float*)d_in[2];  P.pos0 = (const float*)d_in[3];
  P.cls1 = (const float*)d_in[4];  P.reg1 = (const float*)d_in[5];
  P.ctr1 = (const float*)d_in[6];  P.pos1 = (const float*)d_in[7];
  P.cls2 = (const float*)d_in[8];  P.reg2 = (const float*)d_in[9];
  P.ctr2 = (const float*)d_in[10]; P.pos2 = (const float*)d_in[11];
  P.cls3 = (const float*)d_in[12]; P.reg3 = (const float*)d_in[13];
  P.ctr3 = (const float*)d_in[14]; P.pos3 = (const float*)d_in[15];
  P.cls4 = (const float*)d_in[16]; P.reg4 = (const float*)d_in[17];
  P.ctr4 = (const float*)d_in[18]; P.pos4 = (const float*)d_in[19];

  char* ws = (char*)d_ws;
  P.keys0  = (u64*)(ws);
  P.keys1  = (u64*)(ws + 2097152);
  P.keys2  = (u64*)(ws + 2621440);
  P.keys34 = (u64*)(ws + 2752512);
  P.score  = (float*)(ws + 2883584);
  P.clsi   = (unsigned short*)(ws + 3975680);

  // pad all key arrays with all-ones so pads sort last
  (void)hipMemsetAsync(d_ws, 0xFF, 2883584, stream);

  k_score<<<dim3(67, 16), 256, 0, stream>>>(P);
  k_sortchunks<<<112, 1024, 0, stream>>>(P);
  k_merge0<<<16, 1024, 0, stream>>>(P);
  k_nms<<<16, 1024, 0, stream>>>(P, (float*)d_out);
}

// Round 3
// 191.708 us; speedup vs baseline: 2.1651x; 1.1865x over previous
//
#include <hip/hip_runtime.h>
#include <math.h>

#define TOTAL_G 17064
#define NCAND   3064
#define BATCHN  16
#define ALLF    0xFFFFFFFFFFFFFFFFull
// valid <=> score > 0.01f <=> scorebits > 0x3C23D70A <=> hi=~sb < 0xC3DC28F5
#define INVALID_HI 0xC3DC28F5u

typedef unsigned long long u64;

// ws layout (bytes), total 4,521,728 (same as proven R1 size):
//   keys0 : u64[16][16384] @ 0          (2,097,152)
//     overlays (written after keys0 dead, per-image 128KB slots):
//       boxes_b = ws + b*131072          (3064*16 = 49,024 B)
//       mask_b  = ws + b*131072 + 65536  (512*8*8 = 32,768 B)
//   keys1 : u64[16][4096]  @ 2,097,152  (524,288)
//     overlays (per-image 32KB slots):
//       sortedg_b = ws + OFF1 + b*32768          (u16[4096] = 8,192 B)
//       live_b    = ws + OFF1 + b*32768 + 16384  (u64[48])
//   keys2 : u64[16][1024]  @ 2,621,440  (131,072)
//   keys34: u64[16][1024]  @ 2,752,512  (131,072)
//   score : f32[16][17064] @ 2,883,584  (1,092,096)
//   clsi  : u16[16][17064] @ 3,975,680  (546,048)

#define OFF1 2097152

struct Ptrs {
  const float *cls0,*cls1,*cls2,*cls3,*cls4;
  const float *reg0,*reg1,*reg2,*reg3,*reg4;
  const float *ctr0,*ctr1,*ctr2,*ctr3,*ctr4;
  const float *pos0,*pos1,*pos2,*pos3,*pos4;
  u64 *keys0, *keys1, *keys2, *keys34;
  float *score; unsigned short *clsi;
  char *ws;
};

__device__ __forceinline__ float sigd(float x) {
  return (float)(1.0 / (1.0 + exp(-(double)x)));
}
__device__ __forceinline__ float dexp(float x) {
  return (float)exp((double)x);
}
__device__ __forceinline__ void levinfo(int gid, int& lev, int& idx, int& nl) {
  if      (gid < 12800) { lev=0; idx=gid;        nl=12800; }
  else if (gid < 16000) { lev=1; idx=gid-12800;  nl=3200;  }
  else if (gid < 16800) { lev=2; idx=gid-16000;  nl=800;   }
  else if (gid < 17008) { lev=3; idx=gid-16800;  nl=208;   }
  else                  { lev=4; idx=gid-17008;  nl=56;    }
}

__device__ __forceinline__ float* boxes_of(char* ws, int b) {
  return (float*)(ws + (size_t)b * 131072);
}
__device__ __forceinline__ u64* mask_of(char* ws, int b) {
  return (u64*)(ws + (size_t)b * 131072 + 65536);
}
__device__ __forceinline__ unsigned short* sortedg_of(char* ws, int b) {
  return (unsigned short*)(ws + OFF1 + (size_t)b * 32768);
}
__device__ __forceinline__ u64* live_of(char* ws, int b) {
  return (u64*)(ws + OFF1 + (size_t)b * 32768 + 16384);
}

// ---------------- K1: thread-per-position score / argmax / sort-key ----------------
__global__ __launch_bounds__(256) void k_score(Ptrs P) {
  int g = blockIdx.x * 256 + threadIdx.x;
  if (g >= TOTAL_G) return;
  int b = blockIdx.y;

  int lev, idx, nl;
  levinfo(g, lev, idx, nl);
  const float *clsb, *ctrb;
  if      (lev == 0) { clsb = P.cls0; ctrb = P.ctr0; }
  else if (lev == 1) { clsb = P.cls1; ctrb = P.ctr1; }
  else if (lev == 2) { clsb = P.cls2; ctrb = P.ctr2; }
  else if (lev == 3) { clsb = P.cls3; ctrb = P.ctr3; }
  else               { clsb = P.cls4; ctrb = P.ctr4; }

  const float4* cp4 = (const float4*)(clsb + (size_t)(b * nl + idx) * 80);
  float4 q[20];
  #pragma unroll
  for (int k = 0; k < 20; ++k) q[k] = cp4[k];

  // logit max, first-index tie-break (strict >)
  float m = -INFINITY; int mi = 0;
  #pragma unroll
  for (int k = 0; k < 20; ++k) {
    if (q[k].x > m) { m = q[k].x; mi = 4*k+0; }
    if (q[k].y > m) { m = q[k].y; mi = 4*k+1; }
    if (q[k].z > m) { m = q[k].z; mi = 4*k+2; }
    if (q[k].w > m) { m = q[k].w; mi = 4*k+3; }
  }
  // candidates whose fp32 sigmoid could tie the max's sigmoid
  float thr = fminf(m - 1e-3f, 9.0f);
  int cnt = 0;
  #pragma unroll
  for (int k = 0; k < 20; ++k) {
    cnt += (q[k].x >= thr) + (q[k].y >= thr) + (q[k].z >= thr) + (q[k].w >= thr);
  }
  float pmax; int ci;
  if (cnt > 1) {
    // exact per-element sigmoid argmax, first index wins ties
    pmax = -1.0f; ci = 0;
    #pragma unroll
    for (int k = 0; k < 20; ++k) {
      float xs[4] = {q[k].x, q[k].y, q[k].z, q[k].w};
      #pragma unroll
      for (int e = 0; e < 4; ++e) {
        if (xs[e] >= thr) {
          float p = sigd(xs[e]);
          if (p > pmax) { pmax = p; ci = 4*k+e; }
        }
      }
    }
  } else {
    pmax = sigd(m); ci = mi;
  }

  float t = ctrb[(size_t)b * nl + idx];
  float csig = sigd(t);
  float prod = pmax * csig;                 // fp32 mul (matches ref)
  float s = (float)sqrt((double)prod);      // correctly-rounded f32 sqrt
  P.score[(size_t)b * TOTAL_G + g] = s;
  P.clsi [(size_t)b * TOTAL_G + g] = (unsigned short)ci;

  unsigned sb = __float_as_uint(s);
  unsigned hi = ~sb;
  if      (lev == 0) P.keys0 [(size_t)b * 16384 + idx]       = ((u64)hi << 32) | (unsigned)idx;
  else if (lev == 1) P.keys1 [(size_t)b * 4096  + idx]       = ((u64)hi << 32) | (unsigned)idx;
  else if (lev == 2) P.keys2 [(size_t)b * 1024  + idx]       = ((u64)hi << 32) | (unsigned)(2000 + idx);
  else if (lev == 3) P.keys34[(size_t)b * 1024  + idx]       = ((u64)hi << 32) | (unsigned)(2800 + idx);
  else               P.keys34[(size_t)b * 1024  + 208 + idx] = ((u64)hi << 32) | (unsigned)(3008 + idx);
}

// ---------------- bitonic network helpers (in LDS) ----------------
__device__ __forceinline__ void bitonic_range(u64* k, int n, int kk0) {
  for (int kk = kk0; kk <= n; kk <<= 1) {
    for (int j = kk >> 1; j > 0; j >>= 1) {
      for (int t = threadIdx.x; t < n; t += blockDim.x) {
        int ixj = t ^ j;
        if (ixj > t) {
          u64 a = k[t], c = k[ixj];
          bool up = ((t & kk) == 0);
          if ((a > c) == up) { k[t] = c; k[ixj] = a; }
        }
      }
      __syncthreads();
    }
  }
}

// K2a: sort chunks. bid<64: level0 4096-chunks; <80: level1 (4096);
//      <96: level2 (1024); <112: levels3+4 (512 prefix).
__global__ __launch_bounds__(1024) void k_sortchunks(Ptrs P) {
  __shared__ u64 sk[4096];
  int bid = blockIdx.x;
  u64* src; int n;
  if      (bid < 64) { src = P.keys0  + (size_t)(bid >> 2) * 16384 + (size_t)(bid & 3) * 4096; n = 4096; }
  else if (bid < 80) { src = P.keys1  + (size_t)(bid - 64) * 4096; n = 4096; }
  else if (bid < 96) { src = P.keys2  + (size_t)(bid - 80) * 1024; n = 1024; }
  else               { src = P.keys34 + (size_t)(bid - 96) * 1024; n = 512;  }
  for (int t = threadIdx.x; t < n; t += 1024) sk[t] = src[t];
  __syncthreads();
  bitonic_range(sk, n, 2);
  for (int t = threadIdx.x; t < n; t += 1024) src[t] = sk[t];
}

// K2b: merge the four level-0 chunk top-1024s (top-1000 of 12800 is within the
// union). Load asc/desc/asc/desc, run stages kk=2048,4096 (23 passes).
__global__ __launch_bounds__(1024) void k_merge0(Ptrs P) {
  __shared__ u64 sk[4096];
  int b = blockIdx.x;
  u64* base = P.keys0 + (size_t)b * 16384;
  for (int t = threadIdx.x; t < 4096; t += 1024) {
    int blk = t >> 10, pos = t & 1023;
    u64 e = base[(size_t)blk * 4096 + pos];
    int dst = (blk & 1) ? (blk << 10) + (1023 - pos) : t;
    sk[dst] = e;
  }
  __syncthreads();
  bitonic_range(sk, 4096, 2048);
  for (int t = threadIdx.x; t < 4096; t += 1024) base[t] = sk[t];
}

// ---------------- K3a: per-image merge + decode (16 blocks) ----------------
// key lo = (c << 15) | gid  (c < 4096, gid < 17064 < 32768)
__global__ __launch_bounds__(1024) void k_sortdecode(Ptrs P) {
  __shared__ u64 key[4096];
  __shared__ u64 live[48];
  int b = blockIdx.x;
  int tid = threadIdx.x;

  // phase 0: load 4 pre-sorted 1024-blocks as bitonic seq with final keys
  for (int t = tid; t < 4096; t += 1024) {
    int blk = t >> 10, pos = t & 1023;
    u64 e;
    if      (blk == 0) e = (pos < 1000) ? P.keys0[(size_t)b * 16384 + pos] : ALLF;
    else if (blk == 1) e = (pos < 1000) ? P.keys1[(size_t)b * 4096  + pos] : ALLF;
    else if (blk == 2) e = P.keys2 [(size_t)b * 1024 + pos];
    else               e = P.keys34[(size_t)b * 1024 + pos];
    unsigned hi = (unsigned)(e >> 32);
    u64 kk;
    if (hi >= INVALID_HI) kk = ALLF;
    else {
      unsigned lo = (unsigned)e;
      unsigned c, gid;
      if      (blk == 0) { c = pos;        gid = lo; }
      else if (blk == 1) { c = 1000 + pos; gid = 12800 + lo; }
      else               { c = lo;         gid = 14000 + lo; }
      kk = ((u64)hi << 32) | ((u64)c << 15) | gid;
    }
    int dst = (blk & 1) ? (blk << 10) + (1023 - pos) : t;
    key[dst] = kk;
  }
  if (tid < 48) live[tid] = 0ull;
  __syncthreads();

  // phase 1: 23-pass bitonic merge -> (score desc, c asc), invalid last
  bitonic_range(key, 4096, 2048);

  // phase 2: extract gid order + validity
  unsigned short* sg = sortedg_of(P.ws, b);
  for (int r = tid; r < 4096; r += 1024) {
    u64 kk = key[r];
    bool valid = ((unsigned)(kk >> 32)) != 0xFFFFFFFFu;
    sg[r] = valid ? (unsigned short)(kk & 0x7FFF) : (unsigned short)0xFFFF;
    if (r < NCAND && valid) atomicOr(&live[r >> 6], 1ull << (r & 63));
  }
  __syncthreads();
  if (tid < 48) live_of(P.ws, b)[tid] = live[tid];

  // phase 3: decode boxes (gid straight from LDS key)
  float4* boxes4 = (float4*)boxes_of(P.ws, b);
  for (int r = tid; r < NCAND; r += 1024) {
    u64 kk = key[r];
    if (((unsigned)(kk >> 32)) == 0xFFFFFFFFu) {
      boxes4[r] = make_float4(-1e30f, -1e30f, -1e30f, -1e30f);
      continue;
    }
    int gid = (int)(kk & 0x7FFF);
    int lev, idx, nl; levinfo(gid, lev, idx, nl);
    const float *rp, *pp;
    if      (lev == 0) { rp = P.reg0; pp = P.pos0; }
    else if (lev == 1) { rp = P.reg1; pp = P.pos1; }
    else if (lev == 2) { rp = P.reg2; pp = P.pos2; }
    else if (lev == 3) { rp = P.reg3; pp = P.pos3; }
    else               { rp = P.reg4; pp = P.pos4; }
    float4 rv = *(const float4*)(rp + (size_t)(b * nl + idx) * 4);
    float2 pv = *(const float2*)(pp + (size_t)(b * nl + idx) * 2);
    float e0 = dexp(rv.x), e1 = dexp(rv.y), e2 = dexp(rv.z), e3 = dexp(rv.w);
    float x1 = truncf(pv.x - e0), y1 = truncf(pv.y - e1);
    float x2 = truncf(pv.x + e2), y2 = truncf(pv.y + e3);
    x1 = fmaxf(x1, 0.0f); y1 = fmaxf(y1, 0.0f);
    x2 = fminf(x2, 1023.0f); y2 = fminf(y2, 799.0f);
    boxes4[r] = make_float4(x1, y1, x2, y2);
  }
}

// ---------------- K3b: suppression mask, conflict-free (64 blocks) ----------------
// block = (image b, i-quadrant qi). thread: i = qi*128 + (tid>>3), w = tid&7.
// j-scan rotated by w so the 8 w-lanes hit 8 distinct bank groups.
__global__ __launch_bounds__(1024) void k_mask(char* ws) {
  __shared__ float4 sbox[512];
  int b  = blockIdx.x >> 2;
  int qi = blockIdx.x & 3;
  int tid = threadIdx.x;
  const float4* boxes4 = (const float4*)boxes_of(ws, b);
  if (tid < 512) sbox[tid] = boxes4[tid];
  __syncthreads();

  int i = qi * 128 + (tid >> 3);
  int w = tid & 7;
  float4 bi = sbox[i];
  float ia = (bi.z - bi.x) * (bi.w - bi.y);
  u64 mword = 0;
  #pragma unroll 8
  for (int bj = 0; bj < 64; ++bj) {
    int jj = (bj + w) & 63;
    int j = (w << 6) | jj;
    if (j > i) {
      float4 bj4 = sbox[j];
      float ja  = (bj4.z - bj4.x) * (bj4.w - bj4.y);
      float ltx = fmaxf(bi.x, bj4.x), lty = fmaxf(bi.y, bj4.y);
      float rbx = fminf(bi.z, bj4.z), rby = fminf(bi.w, bj4.w);
      float wv = fmaxf(rbx - ltx, 0.0f), hv = fmaxf(rby - lty, 0.0f);
      float inter = wv * hv;
      float iou = inter / (ia + ja - inter);   // exact: integer-valued fp32
      if (iou > 0.6f) mword |= (1ull << jj);
    }
  }
  mask_of(ws, b)[i * 8 + w] = mword;
}

// ---------------- K3c: serial reduce + outputs (16 blocks, 256 thr) ----------------
__global__ __launch_bounds__(256) void k_reduce(Ptrs P, float* out) {
  __shared__ u64 smask[4096];       // 32 KB
  __shared__ u64 live48[48];
  __shared__ unsigned short keeplist[100];
  __shared__ int slotgid[100];
  __shared__ int keptS, curS;
  int b = blockIdx.x;
  int tid = threadIdx.x;
  char* ws = P.ws;

  const u64* gmask = mask_of(ws, b);
  for (int t = tid; t < 4096; t += 256) smask[t] = gmask[t];
  if (tid < 48) live48[tid] = live_of(ws, b)[tid];
  __syncthreads();

  // single-wave barrier-free greedy reduce over ranks [0,512)
  if (tid < 64) {
    int lane = tid;
    u64 lw = (lane < 8) ? live48[lane] : 0ull;
    int kept = 0;
    while (kept < 100) {
      bool nz = (lane < 8) && (lw != 0ull);
      u64 bal = __ballot(nz);
      if (!bal) break;
      int W = __ffsll(bal) - 1;
      u64 wv = __shfl(lw, W);
      int bit = __ffsll(wv) - 1;
      int i = (W << 6) + bit;
      if (lane == 0) keeplist[kept] = (unsigned short)i;
      kept++;
      if (lane == W) lw &= ~(1ull << bit);
      if (kept == 100) break;
      if (lane < 8) lw &= ~smask[i * 8 + lane];
    }
    if (lane == 0) keptS = kept;
  }
  __syncthreads();
  int kept = keptS;

  // fallback: 100th keep beyond rank 512 (rare; must stay exact)
  if (kept < 100) {
    const float4* boxes4 = (const float4*)boxes_of(ws, b);
    for (int k2 = 0; k2 < kept; ++k2) {
      int i = keeplist[k2];
      float4 bi = boxes4[i];
      float ia = (bi.z - bi.x) * (bi.w - bi.y);
      for (int j = 512 + tid; j < NCAND; j += 256) {
        if (!((live48[j >> 6] >> (j & 63)) & 1ull)) continue;
        float4 bj4 = boxes4[j];
        float ja  = (bj4.z - bj4.x) * (bj4.w - bj4.y);
        float ltx = fmaxf(bi.x, bj4.x), lty = fmaxf(bi.y, bj4.y);
        float rbx = fminf(bi.z, bj4.z), rby = fminf(bi.w, bj4.w);
        float wv = fmaxf(rbx - ltx, 0.0f), hv = fmaxf(rby - lty, 0.0f);
        float inter = wv * hv;
        float iou = inter / (ia + ja - inter);
        if (iou > 0.6f) atomicAnd(&live48[j >> 6], ~(1ull << (j & 63)));
      }
    }
    __syncthreads();
    int start = 512;
    while (kept < 100) {
      if (tid == 0) {
        int nxt = -1;
        int w = start >> 6;
        u64 mask = (w < 48) ? (live48[w] & (~0ull << (start & 63))) : 0ull;
        while (w < 48) {
          if (mask) { nxt = (w << 6) + __ffsll(mask) - 1; break; }
          ++w;
          if (w < 48) mask = live48[w];
        }
        curS = nxt;
        if (nxt >= 0) keeplist[kept] = (unsigned short)nxt;
      }
      __syncthreads();
      int i = curS;
      if (i < 0) break;
      float4 bi = boxes4[i];
      float ia = (bi.z - bi.x) * (bi.w - bi.y);
      for (int j = i + 1 + tid; j < NCAND; j += 256) {
        if (!((live48[j >> 6] >> (j & 63)) & 1ull)) continue;
        float4 bj4 = boxes4[j];
        float ja  = (bj4.z - bj4.x) * (bj4.w - bj4.y);
        float ltx = fmaxf(bi.x, bj4.x), lty = fmaxf(bi.y, bj4.y);
        float rbx = fminf(bi.z, bj4.z), rby = fminf(bi.w, bj4.w);
        float wv = fmaxf(rbx - ltx, 0.0f), hv = fmaxf(rby - lty, 0.0f);
        float inter = wv * hv;
        float iou = inter / (ia + ja - inter);
        if (iou > 0.6f) atomicAnd(&live48[j >> 6], ~(1ull << (j & 63)));
      }
      __syncthreads();
      kept++;
      start = i + 1;
    }
  }

  // outputs: out_s @0 [16,100], out_c @1600, out_b @3200 [16,100,4], out_cp @9600
  const unsigned short* sg = sortedg_of(ws, b);
  const float4* boxes4 = (const float4*)boxes_of(ws, b);
  if (tid < 100) {
    int s = tid;
    float os = -1.0f, oc = -1.0f;
    float4 bx = make_float4(-1.0f, -1.0f, -1.0f, -1.0f);
    int gid = -1;
    if (s < kept) {
      int r = keeplist[s];
      gid = sg[r];
      os = P.score[(size_t)b * TOTAL_G + gid];
      oc = (float)P.clsi[(size_t)b * TOTAL_G + gid];
      bx = boxes4[r];
    }
    slotgid[s] = gid;
    out[b * 100 + s] = os;
    out[1600 + b * 100 + s] = oc;
    *(float4*)(out + 3200 + (size_t)(b * 100 + s) * 4) = bx;
  }
  __syncthreads();
  for (int t = tid; t < 100 * 80; t += 256) {
    int s = t / 80, k = t - s * 80;
    float val = -1.0f;
    int gid = slotgid[s];
    if (gid >= 0) {
      int lev, idx, nl; levinfo(gid, lev, idx, nl);
      const float* cp;
      if      (lev == 0) cp = P.cls0;
      else if (lev == 1) cp = P.cls1;
      else if (lev == 2) cp = P.cls2;
      else if (lev == 3) cp = P.cls3;
      else               cp = P.cls4;
      val = sigd(cp[(size_t)(b * nl + idx) * 80 + k]);
    }
    out[9600 + (size_t)(b * 100 + s) * 80 + k] = val;
  }
}

extern "C" void kernel_launch(void* const* d_in, const int* in_sizes, int n_in,
                              void* d_out, int out_size, void* d_ws, size_t ws_size,
                              hipStream_t stream) {
  (void)in_sizes; (void)n_in; (void)out_size; (void)ws_size;
  Ptrs P;
  P.cls0 = (const float*)d_in[0];  P.reg0 = (const float*)d_in[1];
  P.ctr0 = (const float*)d_in[2];  P.pos0 = (const float*)d_in[3];
  P.cls1 = (const float*)d_in[4];  P.reg1 = (const float*)d_in[5];
  P.ctr1 = (const float*)d_in[6];  P.pos1 = (const float*)d_in[7];
  P.cls2 = (const float*)d_in[8];  P.reg2 = (const float*)d_in[9];
  P.ctr2 = (const float*)d_in[10]; P.pos2 = (const float*)d_in[11];
  P.cls3 = (const float*)d_in[12]; P.reg3 = (const float*)d_in[13];
  P.ctr3 = (const float*)d_in[14]; P.pos3 = (const float*)d_in[15];
  P.cls4 = (const float*)d_in[16]; P.reg4 = (const float*)d_in[17];
  P.ctr4 = (const float*)d_in[18]; P.pos4 = (const float*)d_in[19];

  char* ws = (char*)d_ws;
  P.keys0  = (u64*)(ws);
  P.keys1  = (u64*)(ws + OFF1);
  P.keys2  = (u64*)(ws + 2621440);
  P.keys34 = (u64*)(ws + 2752512);
  P.score  = (float*)(ws + 2883584);
  P.clsi   = (unsigned short*)(ws + 3975680);
  P.ws     = ws;

  // pad all key arrays with all-ones so pads sort last
  (void)hipMemsetAsync(d_ws, 0xFF, 2883584, stream);

  k_score<<<dim3(67, 16), 256, 0, stream>>>(P);
  k_sortchunks<<<112, 1024, 0, stream>>>(P);
  k_merge0<<<16, 1024, 0, stream>>>(P);
  k_sortdecode<<<16, 1024, 0, stream>>>(P);
  k_mask<<<64, 1024, 0, stream>>>(ws);
  k_reduce<<<16, 256, 0, stream>>>(P, (float*)d_out);
}

// Round 4
// 184.925 us; speedup vs baseline: 2.2445x; 1.0367x over previous
//
#include <hip/hip_runtime.h>
#include <math.h>

#define TOTAL_G 17064
#define BATCHN  16
#define ALLF    0xFFFFFFFFFFFFFFFFull
// valid <=> score > 0.01f <=> scorebits > 0x3C23D70A <=> (key>>15) < 0xC3DC28F5
#define INVALID_HI 0xC3DC28F5u

typedef unsigned long long u64;
typedef unsigned int u32;

// ---- ws layout (bytes), total 3,421,824 ----
// keys0  : u64[16][12800] @ 0           (dead after k_compact; overlaid below)
//   overlay: mask_b  = ws + b*32768              (16*32768 = 524,288)
//   overlay: boxes_b = ws + 524288 + b*49152     (786,432; ends 1,310,720 < 1,638,400)
// keys1  : u64[16][3200]  @ 1,638,400
// keys234: u64[16][1088]  @ 2,048,000
// T      : u64[2][16]     @ 2,187,264
// Nc     : int[16]        @ 2,187,520
// ckeys  : u64[16][3072]  @ 2,187,648
// sortedg: u16[16][3072]  @ 2,580,864
// clsi   : u16[16][17064] @ 2,679,168
// sorteds: f32[16][3072]  @ 3,225,216
#define KEYS0_OFF   0
#define KEYS1_OFF   1638400
#define KEYS234_OFF 2048000
#define T_OFF       2187264
#define NC_OFF      2187520
#define CK_OFF      2187648
#define SG_OFF      2580864
#define CLSI_OFF    2679168
#define SS_OFF      3225216
#define MASK_OFF    0
#define BOX_OFF     524288

struct Ptrs {
  const float *cls0,*cls1,*cls2,*cls3,*cls4;
  const float *reg0,*reg1,*reg2,*reg3,*reg4;
  const float *ctr0,*ctr1,*ctr2,*ctr3,*ctr4;
  const float *pos0,*pos1,*pos2,*pos3,*pos4;
  char *ws;
};

__device__ __forceinline__ float sigd(float x) {
  return (float)(1.0 / (1.0 + exp(-(double)x)));
}
__device__ __forceinline__ float dexp(float x) {
  return (float)exp((double)x);
}
__device__ __forceinline__ void levinfo(int gid, int& lev, int& idx, int& nl) {
  if      (gid < 12800) { lev=0; idx=gid;        nl=12800; }
  else if (gid < 16000) { lev=1; idx=gid-12800;  nl=3200;  }
  else if (gid < 16800) { lev=2; idx=gid-16000;  nl=800;   }
  else if (gid < 17008) { lev=3; idx=gid-16800;  nl=208;   }
  else                  { lev=4; idx=gid-17008;  nl=56;    }
}

__device__ __forceinline__ u64* mask_of(char* ws, int b) {
  return (u64*)(ws + MASK_OFF + (size_t)b * 32768);
}
__device__ __forceinline__ float4* boxes_of(char* ws, int b) {
  return (float4*)(ws + BOX_OFF + (size_t)b * 49152);
}
__device__ __forceinline__ u64* ckeys_of(char* ws, int b) {
  return (u64*)(ws + CK_OFF + (size_t)b * 24576);
}
__device__ __forceinline__ unsigned short* sortedg_of(char* ws, int b) {
  return (unsigned short*)(ws + SG_OFF + (size_t)b * 6144);
}
__device__ __forceinline__ float* sorteds_of(char* ws, int b) {
  return (float*)(ws + SS_OFF + (size_t)b * 12288);
}

// ---------------- K1: per-position score / argmax / key ----------------
__global__ __launch_bounds__(256) void k_score(Ptrs P) {
  int g = blockIdx.x * 256 + threadIdx.x;
  if (g >= TOTAL_G) return;
  int b = blockIdx.y;

  int lev, idx, nl;
  levinfo(g, lev, idx, nl);
  const float *clsb, *ctrb;
  if      (lev == 0) { clsb = P.cls0; ctrb = P.ctr0; }
  else if (lev == 1) { clsb = P.cls1; ctrb = P.ctr1; }
  else if (lev == 2) { clsb = P.cls2; ctrb = P.ctr2; }
  else if (lev == 3) { clsb = P.cls3; ctrb = P.ctr3; }
  else               { clsb = P.cls4; ctrb = P.ctr4; }

  const float4* cp4 = (const float4*)(clsb + (size_t)(b * nl + idx) * 80);
  // incremental top-2 (m, m2) + first-index strict argmax
  float m = -INFINITY, m2 = -INFINITY; int mi = 0;
  #pragma unroll
  for (int k = 0; k < 20; ++k) {
    float4 v = cp4[k];
    if (v.x > m) { m2 = m; m = v.x; mi = 4*k+0; } else if (v.x > m2) m2 = v.x;
    if (v.y > m) { m2 = m; m = v.y; mi = 4*k+1; } else if (v.y > m2) m2 = v.y;
    if (v.z > m) { m2 = m; m = v.z; mi = 4*k+2; } else if (v.z > m2) m2 = v.z;
    if (v.w > m) { m2 = m; m = v.w; mi = 4*k+3; } else if (v.w > m2) m2 = v.w;
  }
  // sigmoid-tie candidate band (same proven logic as before: cnt>1 <=> m2>=thr)
  float thr = fminf(m - 1e-3f, 9.0f);
  float pmax; int ci;
  if (m2 >= thr) {
    // rare exact path: per-element sigmoid argmax among candidates >= thr
    pmax = -1.0f; ci = 0;
    #pragma unroll 4
    for (int k = 0; k < 20; ++k) {
      float4 v = cp4[k];
      float xs[4] = {v.x, v.y, v.z, v.w};
      #pragma unroll
      for (int e = 0; e < 4; ++e) {
        if (xs[e] >= thr) {
          float p = sigd(xs[e]);
          if (p > pmax) { pmax = p; ci = 4*k+e; }
        }
      }
    }
  } else {
    pmax = sigd(m); ci = mi;
  }

  float t = ctrb[(size_t)b * nl + idx];
  float csig = sigd(t);
  float prod = pmax * csig;
  float s = (float)sqrt((double)prod);
  ((unsigned short*)(P.ws + CLSI_OFF))[(size_t)b * TOTAL_G + g] = (unsigned short)ci;

  unsigned hi = ~__float_as_uint(s);
  u64 key = ((u64)hi << 15) | (unsigned)g;   // global NMS-order key
  if      (lev == 0) ((u64*)(P.ws + KEYS0_OFF))  [(size_t)b * 12800 + idx] = key;
  else if (lev == 1) ((u64*)(P.ws + KEYS1_OFF))  [(size_t)b * 3200  + idx] = key;
  else               ((u64*)(P.ws + KEYS234_OFF))[(size_t)b * 1088  + (g - 16000)] = key;
}

// ---------------- K2: radix-select exact 1000th-smallest key per (b, lev) ----------------
__global__ __launch_bounds__(1024) void k_sel(Ptrs P) {
  __shared__ u32 hist[8][4096];       // 128 KB, 8 replicas vs clustered-score contention
  __shared__ u64 bcastP;
  __shared__ int bcastT;
  int b = blockIdx.x, lev = blockIdx.y;
  const u64* keys = lev ? ((u64*)(P.ws + KEYS1_OFF) + (size_t)b * 3200)
                        : ((u64*)(P.ws + KEYS0_OFF) + (size_t)b * 12800);
  int n = lev ? 3200 : 12800;
  int tid = threadIdx.x, wid = tid >> 6, lane = tid & 63;
  int rep = wid & 7;

  u64 Pfx = 0; int t = 1000;
  const int S[4] = {35, 23, 11, 0};
  const int W[4] = {12, 12, 12, 11};
  #pragma unroll 1
  for (int p = 0; p < 4; ++p) {
    int s = S[p], wb = W[p];
    u32 dmask = (1u << wb) - 1u;
    for (int i = tid; i < 8 * 4096; i += 1024) (&hist[0][0])[i] = 0;
    __syncthreads();
    for (int i = tid; i < n; i += 1024) {
      u64 k = keys[i];
      if ((k >> (s + wb)) == Pfx) {
        u32 d = (u32)(k >> s) & dmask;
        atomicAdd(&hist[rep][d], 1u);
      }
    }
    __syncthreads();
    // fold replicas into replica 0
    for (int i = tid; i < 4096; i += 1024) {
      u32 v = hist[0][i];
      #pragma unroll
      for (int r = 1; r < 8; ++r) v += hist[r][i];
      hist[0][i] = v;
    }
    __syncthreads();
    // single-wave two-level cumsum search for bin where cum crosses t
    if (wid == 0) {
      u32 ssum = 0;
      #pragma unroll 8
      for (int i = 0; i < 64; ++i) {
        int ii = (i + lane) & 63;                  // rotate: avoid same-bank column
        ssum += hist[0][(lane << 6) + ii];
      }
      u32 inc = ssum;
      for (int o = 1; o < 64; o <<= 1) {
        u32 v = __shfl_up(inc, o);
        if (lane >= o) inc += v;
      }
      u64 ball = __ballot(inc >= (u32)t);
      int Ws = __ffsll(ball) - 1;
      u32 cumBefore = __shfl(inc - ssum, Ws);
      u32 v2 = hist[0][(Ws << 6) + lane];
      u32 inc2 = v2;
      for (int o = 1; o < 64; o <<= 1) {
        u32 x = __shfl_up(inc2, o);
        if (lane >= o) inc2 += x;
      }
      u64 ball2 = __ballot(cumBefore + inc2 >= (u32)t);
      int l2 = __ffsll(ball2) - 1;
      u32 cumB2 = __shfl(cumBefore + inc2 - v2, l2);
      if (lane == 0) {
        int d = (Ws << 6) + l2;
        bcastP = (Pfx << wb) | (u32)d;
        bcastT = t - (int)cumB2;
      }
    }
    __syncthreads();
    Pfx = bcastP; t = bcastT;
    __syncthreads();
  }
  if (tid == 0) ((u64*)(P.ws + T_OFF))[lev * 16 + b] = Pfx;
}

// ---------------- K3: deterministic compaction of surviving candidates ----------------
__device__ __forceinline__ u64 loadkey(const Ptrs& P, int b, int u) {
  if (u < 12800) return ((const u64*)(P.ws + KEYS0_OFF))  [(size_t)b * 12800 + u];
  if (u < 16000) return ((const u64*)(P.ws + KEYS1_OFF))  [(size_t)b * 3200  + (u - 12800)];
  return               ((const u64*)(P.ws + KEYS234_OFF))[(size_t)b * 1088  + (u - 16000)];
}

__global__ __launch_bounds__(1024) void k_compact(Ptrs P) {
  __shared__ int wbase[17 * 16 + 1];
  int b = blockIdx.x;
  int tid = threadIdx.x, wid = tid >> 6, lane = tid & 63;
  u64 T0 = ((u64*)(P.ws + T_OFF))[b];
  u64 T1 = ((u64*)(P.ws + T_OFF))[16 + b];

  for (int it = 0; it < 17; ++it) {
    int u = it * 1024 + tid;
    bool keep = false;
    if (u < TOTAL_G) {
      u64 k = loadkey(P, b, u);
      bool valid = (u32)(k >> 15) < INVALID_HI;
      bool sel = (u < 12800) ? (k <= T0) : ((u < 16000) ? (k <= T1) : true);
      keep = valid && sel;
    }
    u64 bal = __ballot(keep);
    if (lane == 0) wbase[it * 16 + wid] = __popcll(bal);
  }
  __syncthreads();
  if (tid == 0) {
    int run = 0;
    for (int i = 0; i < 272; ++i) { int c = wbase[i]; wbase[i] = run; run += c; }
    ((int*)(P.ws + NC_OFF))[b] = run;
  }
  __syncthreads();
  u64* ck = ckeys_of(P.ws, b);
  for (int it = 0; it < 17; ++it) {
    int u = it * 1024 + tid;
    bool keep = false; u64 k = 0;
    if (u < TOTAL_G) {
      k = loadkey(P, b, u);
      bool valid = (u32)(k >> 15) < INVALID_HI;
      bool sel = (u < 12800) ? (k <= T0) : ((u < 16000) ? (k <= T1) : true);
      keep = valid && sel;
    }
    u64 bal = __ballot(keep);
    int pos = wbase[it * 16 + wid] + __popcll(bal & ((1ull << lane) - 1ull));
    if (keep) ck[pos] = k;
  }
}

// ---------------- K4: rank-by-counting + box decode ----------------
// grid (12, 16): part, image. 1024 threads: cand = part*256 + (tid&255), seg = tid>>8.
__global__ __launch_bounds__(1024) void k_rankdecode(Ptrs P) {
  __shared__ u64 skey[3072];
  __shared__ unsigned short parts[1024];
  int part = blockIdx.x, b = blockIdx.y;
  int tid = threadIdx.x;
  int Nc = ((int*)(P.ws + NC_OFF))[b];
  const u64* ck = ckeys_of(P.ws, b);
  for (int t = tid; t < Nc; t += 1024) skey[t] = ck[t];
  __syncthreads();

  int ci = (part << 8) + (tid & 255);
  int seg = tid >> 8;
  u64 my = (ci < Nc) ? skey[ci] : ALLF;
  int jlen = (Nc + 3) >> 2;
  int jb = seg * jlen;
  int je = jb + jlen; if (je > Nc) je = Nc;
  int cnt = 0;
  #pragma unroll 4
  for (int j = jb; j < je; ++j) cnt += (skey[j] < my) ? 1 : 0;
  parts[tid] = (unsigned short)cnt;
  __syncthreads();

  if (seg == 0 && ci < Nc) {
    int r = cnt + parts[tid + 256] + parts[tid + 512] + parts[tid + 768];
    int gid = (int)(my & 0x7FFF);
    int lev, idx, nl; levinfo(gid, lev, idx, nl);
    const float *rp, *pp;
    if      (lev == 0) { rp = P.reg0; pp = P.pos0; }
    else if (lev == 1) { rp = P.reg1; pp = P.pos1; }
    else if (lev == 2) { rp = P.reg2; pp = P.pos2; }
    else if (lev == 3) { rp = P.reg3; pp = P.pos3; }
    else               { rp = P.reg4; pp = P.pos4; }
    float4 rv = *(const float4*)(rp + (size_t)(b * nl + idx) * 4);
    float2 pv = *(const float2*)(pp + (size_t)(b * nl + idx) * 2);
    float e0 = dexp(rv.x), e1 = dexp(rv.y), e2 = dexp(rv.z), e3 = dexp(rv.w);
    float x1 = truncf(pv.x - e0), y1 = truncf(pv.y - e1);
    float x2 = truncf(pv.x + e2), y2 = truncf(pv.y + e3);
    x1 = fmaxf(x1, 0.0f); y1 = fmaxf(y1, 0.0f);
    x2 = fminf(x2, 1023.0f); y2 = fminf(y2, 799.0f);
    boxes_of(P.ws, b)[r] = make_float4(x1, y1, x2, y2);
    sortedg_of(P.ws, b)[r] = (unsigned short)gid;
    sorteds_of(P.ws, b)[r] = __uint_as_float(~(u32)(my >> 15));
  }
}

// ---------------- K5: suppression mask for top-512 ranks (rotated, conflict-free) ----------------
__global__ __launch_bounds__(1024) void k_mask(char* ws) {
  __shared__ float4 sbox[512];
  int qi = blockIdx.x, b = blockIdx.y;
  int tid = threadIdx.x;
  int Nc = ((int*)(ws + NC_OFF))[b];
  const float4* boxes4 = boxes_of(ws, b);
  if (tid < 512)
    sbox[tid] = (tid < Nc) ? boxes4[tid] : make_float4(-1e30f, -1e30f, -1e30f, -1e30f);
  __syncthreads();

  int i = qi * 128 + (tid >> 3);
  int w = tid & 7;
  float4 bi = sbox[i];
  float ia = (bi.z - bi.x) * (bi.w - bi.y);
  u64 mword = 0;
  #pragma unroll 8
  for (int bj = 0; bj < 64; ++bj) {
    int jj = (bj + w) & 63;
    int j = (w << 6) | jj;
    if (j > i) {
      float4 bj4 = sbox[j];
      float ja  = (bj4.z - bj4.x) * (bj4.w - bj4.y);
      float ltx = fmaxf(bi.x, bj4.x), lty = fmaxf(bi.y, bj4.y);
      float rbx = fminf(bi.z, bj4.z), rby = fminf(bi.w, bj4.w);
      float wv = fmaxf(rbx - ltx, 0.0f), hv = fmaxf(rby - lty, 0.0f);
      float inter = wv * hv;
      float iou = inter / (ia + ja - inter);   // exact: integer-valued fp32
      if (iou > 0.6f) mword |= (1ull << jj);
    }
  }
  mask_of(ws, b)[i * 8 + w] = mword;
}

// ---------------- K6: serial greedy reduce + outputs ----------------
__global__ __launch_bounds__(256) void k_reduce(Ptrs P, float* out) {
  __shared__ u64 smask[4096];       // 32 KB
  __shared__ u64 live48[48];
  __shared__ unsigned short keeplist[100];
  __shared__ int slotgid[100];
  __shared__ int keptS, curS;
  int b = blockIdx.x;
  int tid = threadIdx.x;
  char* ws = P.ws;
  int Nc = ((int*)(ws + NC_OFF))[b];

  const u64* gmask = mask_of(ws, b);
  for (int t = tid; t < 4096; t += 256) smask[t] = gmask[t];
  if (tid < 48) {
    int lo = tid << 6;
    int c = Nc - lo; if (c < 0) c = 0; if (c > 64) c = 64;
    live48[tid] = (c >= 64) ? ALLF : ((c > 0) ? ((1ull << c) - 1ull) : 0ull);
  }
  __syncthreads();

  // single-wave barrier-free greedy reduce over ranks [0,512)
  if (tid < 64) {
    int lane = tid;
    int n512 = (Nc < 512) ? Nc : 512;
    u64 lw = 0;
    if (lane < 8) {
      int lo = lane << 6;
      int c = n512 - lo; if (c < 0) c = 0; if (c > 64) c = 64;
      lw = (c >= 64) ? ALLF : ((c > 0) ? ((1ull << c) - 1ull) : 0ull);
    }
    int kept = 0;
    while (kept < 100) {
      bool nz = (lane < 8) && (lw != 0ull);
      u64 bal = __ballot(nz);
      if (!bal) break;
      int W = __ffsll(bal) - 1;
      u64 wv = __shfl(lw, W);
      int bit = __ffsll(wv) - 1;
      int i = (W << 6) + bit;
      if (lane == 0) keeplist[kept] = (unsigned short)i;
      kept++;
      if (lane == W) lw &= ~(1ull << bit);
      if (kept == 100) break;
      if (lane < 8) lw &= ~smask[i * 8 + lane];
    }
    if (lane == 0) keptS = kept;
  }
  __syncthreads();
  int kept = keptS;

  // fallback: 100th keep beyond rank 512 (rare; exact)
  if (kept < 100 && Nc > 512) {
    const float4* boxes4 = boxes_of(ws, b);
    for (int k2 = 0; k2 < kept; ++k2) {
      int i = keeplist[k2];
      float4 bi = boxes4[i];
      float ia = (bi.z - bi.x) * (bi.w - bi.y);
      for (int j = 512 + tid; j < Nc; j += 256) {
        if (!((live48[j >> 6] >> (j & 63)) & 1ull)) continue;
        float4 bj4 = boxes4[j];
        float ja  = (bj4.z - bj4.x) * (bj4.w - bj4.y);
        float ltx = fmaxf(bi.x, bj4.x), lty = fmaxf(bi.y, bj4.y);
        float rbx = fminf(bi.z, bj4.z), rby = fminf(bi.w, bj4.w);
        float wv = fmaxf(rbx - ltx, 0.0f), hv = fmaxf(rby - lty, 0.0f);
        float inter = wv * hv;
        float iou = inter / (ia + ja - inter);
        if (iou > 0.6f) atomicAnd(&live48[j >> 6], ~(1ull << (j & 63)));
      }
    }
    __syncthreads();
    int start = 512;
    while (kept < 100) {
      if (tid == 0) {
        int nxt = -1;
        int w = start >> 6;
        u64 mask = (w < 48) ? (live48[w] & (~0ull << (start & 63))) : 0ull;
        while (w < 48) {
          if (mask) { nxt = (w << 6) + __ffsll(mask) - 1; break; }
          ++w;
          if (w < 48) mask = live48[w];
        }
        curS = nxt;
        if (nxt >= 0) keeplist[kept] = (unsigned short)nxt;
      }
      __syncthreads();
      int i = curS;
      if (i < 0) break;
      float4 bi = boxes4[i];
      float ia = (bi.z - bi.x) * (bi.w - bi.y);
      for (int j = i + 1 + tid; j < Nc; j += 256) {
        if (!((live48[j >> 6] >> (j & 63)) & 1ull)) continue;
        float4 bj4 = boxes4[j];
        float ja  = (bj4.z - bj4.x) * (bj4.w - bj4.y);
        float ltx = fmaxf(bi.x, bj4.x), lty = fmaxf(bi.y, bj4.y);
        float rbx = fminf(bi.z, bj4.z), rby = fminf(bi.w, bj4.w);
        float wv = fmaxf(rbx - ltx, 0.0f), hv = fmaxf(rby - lty, 0.0f);
        float inter = wv * hv;
        float iou = inter / (ia + ja - inter);
        if (iou > 0.6f) atomicAnd(&live48[j >> 6], ~(1ull << (j & 63)));
      }
      __syncthreads();
      kept++;
      start = i + 1;
    }
  }

  // outputs: out_s @0 [16,100], out_c @1600, out_b @3200 [16,100,4], out_cp @9600
  const unsigned short* sg = sortedg_of(ws, b);
  const float* ss = sorteds_of(ws, b);
  const float4* boxes4 = boxes_of(ws, b);
  if (tid < 100) {
    int s = tid;
    float os = -1.0f, oc = -1.0f;
    float4 bx = make_float4(-1.0f, -1.0f, -1.0f, -1.0f);
    int gid = -1;
    if (s < kept) {
      int r = keeplist[s];
      gid = sg[r];
      os = ss[r];
      oc = (float)((unsigned short*)(ws + CLSI_OFF))[(size_t)b * TOTAL_G + gid];
      bx = boxes4[r];
    }
    slotgid[s] = gid;
    out[b * 100 + s] = os;
    out[1600 + b * 100 + s] = oc;
    *(float4*)(out + 3200 + (size_t)(b * 100 + s) * 4) = bx;
  }
  __syncthreads();
  for (int t = tid; t < 100 * 80; t += 256) {
    int s = t / 80, k = t - s * 80;
    float val = -1.0f;
    int gid = slotgid[s];
    if (gid >= 0) {
      int lev, idx, nl; levinfo(gid, lev, idx, nl);
      const float* cp;
      if      (lev == 0) cp = P.cls0;
      else if (lev == 1) cp = P.cls1;
      else if (lev == 2) cp = P.cls2;
      else if (lev == 3) cp = P.cls3;
      else               cp = P.cls4;
      val = sigd(cp[(size_t)(b * nl + idx) * 80 + k]);
    }
    out[9600 + (size_t)(b * 100 + s) * 80 + k] = val;
  }
}

extern "C" void kernel_launch(void* const* d_in, const int* in_sizes, int n_in,
                              void* d_out, int out_size, void* d_ws, size_t ws_size,
                              hipStream_t stream) {
  (void)in_sizes; (void)n_in; (void)out_size; (void)ws_size;
  Ptrs P;
  P.cls0 = (const float*)d_in[0];  P.reg0 = (const float*)d_in[1];
  P.ctr0 = (const float*)d_in[2];  P.pos0 = (const float*)d_in[3];
  P.cls1 = (const float*)d_in[4];  P.reg1 = (const float*)d_in[5];
  P.ctr1 = (const float*)d_in[6];  P.pos1 = (const float*)d_in[7];
  P.cls2 = (const float*)d_in[8];  P.reg2 = (const float*)d_in[9];
  P.ctr2 = (const float*)d_in[10]; P.pos2 = (const float*)d_in[11];
  P.cls3 = (const float*)d_in[12]; P.reg3 = (const float*)d_in[13];
  P.ctr3 = (const float*)d_in[14]; P.pos3 = (const float*)d_in[15];
  P.cls4 = (const float*)d_in[16]; P.reg4 = (const float*)d_in[17];
  P.ctr4 = (const float*)d_in[18]; P.pos4 = (const float*)d_in[19];
  P.ws = (char*)d_ws;

  k_score<<<dim3(67, 16), 256, 0, stream>>>(P);
  k_sel<<<dim3(16, 2), 1024, 0, stream>>>(P);
  k_compact<<<16, 1024, 0, stream>>>(P);
  k_rankdecode<<<dim3(12, 16), 1024, 0, stream>>>(P);
  k_mask<<<dim3(4, 16), 1024, 0, stream>>>((char*)d_ws);
  k_reduce<<<16, 256, 0, stream>>>(P, (float*)d_out);
}